// Round 7
// baseline (258.881 us; speedup 1.0000x reference)
//
#include <hip/hip_runtime.h>
#include <hip/hip_bf16.h>
#include <math.h>

// Problem constants (fixed by reference setup_inputs)
#define BB 16
#define NN 64
#define ATTR 4
#define STATE 16
#define RELD 9
#define GG 32
#define NF 256
#define NROWS_OBJ (BB*NN)        // 1024
#define NROWS_REL (BB*NN*NN)     // 65536

typedef _Float16 half8 __attribute__((ext_vector_type(8)));
typedef _Float16 half4 __attribute__((ext_vector_type(4)));
typedef float  floatx4 __attribute__((ext_vector_type(4)));

// fp16 split: x ~= h + l, |x-(h+l)| ~ 2^-22 |x| (A-operand use only)
__device__ __forceinline__ void split2h(float x, _Float16& h, _Float16& l) {
  h = (_Float16)x;
  l = (_Float16)(x - (float)h);
}

#define F0_ELEMS (2 * 16 * 64 * 8)   // 16384
#define F1_ELEMS (8 * 16 * 64 * 8)   // 65536
#define F_TOTAL  (F0_ELEMS + 2 * F1_ELEMS)

// ---------------------------------------------------------------------------
// R22: obj chain rebuilt as 2D-TILED GEMM kernels.  R21 falsified the
// outstanding-load theory; the real limit is ~25 GB/s/CU (=10 B/cyc) on
// UNIQUE (L1-missing) bytes.  Read-once-per-block = 1 MB/CU = 40 us/kernel.
// 32x32 output tiles cut unique bytes to K*32*4 (W) + 32*K*4 (act) =
// 64-160 KB/block -> 3-7 us/phase.  Fusion boundaries become dispatches
// (9 total); graph dispatch ~2 us each.  All fp32, 4-seg k-split + LDS
// reduce (R20-proven).  A-tile LDS stride 516/260: stride%32=4 spreads the
// 8 wave-rows across banks (conflict-free broadcast reads).
// ---------------------------------------------------------------------------

// 4-col partial dot: thread (kseg,r,cg) accumulates cols [col..col+3] of
// row r over k in [kbase, kbase+4*nq). W row-stride ws.
__device__ __forceinline__ floatx4 tile_part(const float* __restrict__ W, int ws,
                                             const float* A, int as,
                                             int kbase, int nq, int r, int col)
{
  floatx4 acc = (floatx4)(0.f);
#pragma unroll 4
  for (int q = 0; q < nq; ++q) {
    int kk = kbase + q * 4;
    floatx4 a4 = *(const floatx4*)(A + r * as + kk);
    acc += a4[0] * *(const floatx4*)(W + (size_t)(kk + 0) * ws + col);
    acc += a4[1] * *(const floatx4*)(W + (size_t)(kk + 1) * ws + col);
    acc += a4[2] * *(const floatx4*)(W + (size_t)(kk + 2) * ws + col);
    acc += a4[3] * *(const floatx4*)(W + (size_t)(kk + 3) * ws + col);
  }
  return acc;
}

__device__ __forceinline__ floatx4 relu4(floatx4 v) {
  v[0] = fmaxf(v[0], 0.f); v[1] = fmaxf(v[1], 0.f);
  v[2] = fmaxf(v[2], 0.f); v[3] = fmaxf(v[3], 0.f);
  return v;
}

#define RED4(ks, rr, cc) (*(const floatx4*)(&red[(((ks)*32+(rr))*8+(cc))*4]))

// ---------------------------------------------------------------------------
// enc_obj: F-prep + H(32x256) + obj0 32x32 tile.  grid 256 = 32 Mt x 8 Nt.
// ---------------------------------------------------------------------------
__global__ __launch_bounds__(1024) void enc_obj_kernel(
    const float* __restrict__ attrs, const float* __restrict__ states,
    const float* __restrict__ w0, const float* __restrict__ b0,
    const float* __restrict__ w1, const float* __restrict__ b1,
    const float* __restrict__ rpw,
    const float* __restrict__ rel_w0, const float* __restrict__ rel_w1,
    _Float16* __restrict__ F0, _Float16* __restrict__ F1,
    _Float16* __restrict__ F2, float* __restrict__ obj)
{
  int tid = threadIdx.x;
  {
    int idx = blockIdx.x * 1024 + tid;   // 262144 threads >= F_TOTAL
    if (idx < F0_ELEMS) {
      int j = idx & 7, lane = (idx >> 3) & 63, g = (idx >> 9) & 15, s = idx >> 13;
      int k = s * 32 + (lane >> 4) * 8 + j, n = g * 16 + (lane & 15);
      float v = (k < 33) ? rel_w0[k * NF + n] : 0.f;
      F0[idx] = (_Float16)v;
    } else if (idx < F0_ELEMS + F1_ELEMS) {
      int t = idx - F0_ELEMS;
      int j = t & 7, lane = (t >> 3) & 63, g = (t >> 9) & 15, s = t >> 13;
      int k = s * 32 + (lane >> 4) * 8 + j, n = g * 16 + (lane & 15);
      F1[t] = (_Float16)rel_w1[k * NF + n];
    } else if (idx < F_TOTAL) {
      int t = idx - (F0_ELEMS + F1_ELEMS);
      int j = t & 7, lane = (t >> 3) & 63, g = (t >> 9) & 15, s = t >> 13;
      int k = s * 32 + (lane >> 4) * 8 + j, n = g * 16 + (lane & 15);
      F2[t] = (_Float16)rpw[k * NF + n];
    }
  }
  __shared__ float X[32 * 20];
  __shared__ __align__(16) float H[32 * 260];
  __shared__ __align__(16) float red[4096];
  int mt = blockIdx.x >> 3, nt = blockIdx.x & 7;
  int row0 = mt * 32;
  for (int idx = tid; idx < 32 * 20; idx += 1024) {
    int rr = idx / 20, k = idx % 20;
    int m = row0 + rr;
    X[idx] = (k < ATTR) ? attrs[m * ATTR + k] : states[m * STATE + (k - ATTR)];
  }
  __syncthreads();
  // H = ReLU(X @ w0 + b0), full 256 cols (w0 is 20 KB: cheap to re-read)
  for (int idx = tid; idx < 2048; idx += 1024) {
    int rr = idx >> 6, cc = (idx & 63) * 4;
    floatx4 a = *(const floatx4*)(b0 + cc);
#pragma unroll
    for (int k = 0; k < 20; ++k)
      a += X[rr * 20 + k] * *(const floatx4*)(w0 + k * NF + cc);
    *(floatx4*)(H + rr * 260 + cc) = relu4(a);
  }
  __syncthreads();
  int kseg = tid >> 8, r = (tid >> 3) & 31, cg = tid & 7;
  int col = nt * 32 + cg * 4;
  floatx4 acc = tile_part(w1, NF, H, 260, kseg * 64, 16, r, col);
  *(floatx4*)(&red[((kseg * 32 + r) * 8 + cg) * 4]) = acc;
  __syncthreads();
  if (tid < 256) {
    int rr = tid >> 3, cc = tid & 7;
    int col2 = nt * 32 + cc * 4;
    floatx4 s = RED4(0, rr, cc) + RED4(1, rr, cc) + RED4(2, rr, cc) + RED4(3, rr, cc)
              + *(const floatx4*)(b1 + col2);
    *(floatx4*)(obj + (size_t)(row0 + rr) * NF + col2) = relu4(s);
  }
}

// ---------------------------------------------------------------------------
// qr: [Q|R] = obj @ rpw_recv/send (+rpb for Q).  grid 512 = 32 Mt x 16 Nt.
// ---------------------------------------------------------------------------
__global__ __launch_bounds__(1024) void qr_kernel(
    const float* __restrict__ objp, const float* __restrict__ rpw,
    const float* __restrict__ rpb,
    float* __restrict__ Qo, float* __restrict__ Ro)
{
  __shared__ __align__(16) float A[32 * 260];
  __shared__ __align__(16) float red[4096];
  int tid = threadIdx.x;
  int mt = blockIdx.x >> 4, nt = blockIdx.x & 15;
  int row0 = mt * 32;
  for (int idx = tid; idx < 2048; idx += 1024) {
    int rr = idx >> 6, q = idx & 63;
    *(floatx4*)(A + rr * 260 + q * 4) =
        *(const floatx4*)(objp + (size_t)(row0 + rr) * NF + q * 4);
  }
  __syncthreads();
  int kseg = tid >> 8, r = (tid >> 3) & 31, cg = tid & 7;
  int col512 = nt * 32 + cg * 4;
  const float* W = (nt < 8) ? (rpw + 256 * NF) : (rpw + 512 * NF);
  int wcol = (nt < 8) ? col512 : (col512 - 256);
  floatx4 acc = tile_part(W, NF, A, 260, kseg * 64, 16, r, wcol);
  *(floatx4*)(&red[((kseg * 32 + r) * 8 + cg) * 4]) = acc;
  __syncthreads();
  if (tid < 256) {
    int rr = tid >> 3, cc = tid & 7;
    int c512 = nt * 32 + cc * 4;
    floatx4 s = RED4(0, rr, cc) + RED4(1, rr, cc) + RED4(2, rr, cc) + RED4(3, rr, cc);
    if (nt < 8) {
      s += *(const floatx4*)(rpb + c512);
      *(floatx4*)(Qo + (size_t)(row0 + rr) * NF + c512) = s;
    } else {
      *(floatx4*)(Ro + (size_t)(row0 + rr) * NF + (c512 - 256)) = s;
    }
  }
}

// ---------------------------------------------------------------------------
// upd: obj_out = ReLU([objp | G] @ ppw + ppb).  G = part[2i]+part[2i+1]
// (gsum2=1) or gA rows (gsum2=0).  grid 256 = 32 Mt x 8 Nt.  K=512.
// ---------------------------------------------------------------------------
__global__ __launch_bounds__(1024) void upd_kernel(
    const float* __restrict__ objp, const float* __restrict__ gA, int gsum2,
    const float* __restrict__ ppw, const float* __restrict__ ppb,
    float* __restrict__ obj_out)
{
  __shared__ __align__(16) float A[32 * 516];
  __shared__ __align__(16) float red[4096];
  int tid = threadIdx.x;
  int mt = blockIdx.x >> 3, nt = blockIdx.x & 7;
  int row0 = mt * 32;
  for (int idx = tid; idx < 4096; idx += 1024) {
    int rr = idx >> 7, q = idx & 127;
    floatx4 v;
    if (q < 64) {
      v = *(const floatx4*)(objp + (size_t)(row0 + rr) * NF + q * 4);
    } else {
      int cc = (q - 64) * 4;
      if (gsum2)
        v = *(const floatx4*)(gA + ((size_t)(row0 + rr) * 2) * NF + cc)
          + *(const floatx4*)(gA + ((size_t)(row0 + rr) * 2 + 1) * NF + cc);
      else
        v = *(const floatx4*)(gA + (size_t)(row0 + rr) * NF + cc);
    }
    *(floatx4*)(A + rr * 516 + q * 4) = v;
  }
  __syncthreads();
  int kseg = tid >> 8, r = (tid >> 3) & 31, cg = tid & 7;
  int col = nt * 32 + cg * 4;
  floatx4 acc = tile_part(ppw, NF, A, 516, kseg * 128, 32, r, col);
  *(floatx4*)(&red[((kseg * 32 + r) * 8 + cg) * 4]) = acc;
  __syncthreads();
  if (tid < 256) {
    int rr = tid >> 3, cc = tid & 7;
    int col2 = nt * 32 + cc * 4;
    floatx4 s = RED4(0, rr, cc) + RED4(1, rr, cc) + RED4(2, rr, cc) + RED4(3, rr, cc)
              + *(const floatx4*)(ppb + col2);
    *(floatx4*)(obj_out + (size_t)(row0 + rr) * NF + col2) = relu4(s);
  }
}

// ---------------------------------------------------------------------------
// aggsweep: G2[i][c] = sum_j ReLU(P[i][j][c] + Q1[i][c] + R1[b,j][c]).
// grid 256 = 32 Mt x 8 Nt; 4 j-segments of 16 + LDS reduce (same fp32
// grouping as the R15 sweep).
// ---------------------------------------------------------------------------
__global__ __launch_bounds__(1024) void aggsweep_kernel(
    const _Float16* __restrict__ P, const float* __restrict__ Q1,
    const float* __restrict__ R1, float* __restrict__ G2)
{
  __shared__ __align__(16) float red[4096];
  int tid = threadIdx.x;
  int mt = blockIdx.x >> 3, nt = blockIdx.x & 7;
  int row0 = mt * 32;
  int b = row0 >> 6;
  int jseg = tid >> 8, r = (tid >> 3) & 31, cg = tid & 7;
  int col = nt * 32 + cg * 4;
  int i = row0 + r;
  floatx4 q4 = *(const floatx4*)(Q1 + (size_t)i * NF + col);
  const _Float16* Pb = P + ((size_t)i * NN + jseg * 16) * NF + col;
  const float* Rb = R1 + ((size_t)(b * NN) + jseg * 16) * NF + col;
  floatx4 s = (floatx4)(0.f);
#pragma unroll
  for (int j = 0; j < 16; ++j) {
    half4 ph = *(const half4*)(Pb + (size_t)j * NF);
    floatx4 rv = *(const floatx4*)(Rb + (size_t)j * NF);
    s[0] += fmaxf((float)ph[0] + q4[0] + rv[0], 0.f);
    s[1] += fmaxf((float)ph[1] + q4[1] + rv[1], 0.f);
    s[2] += fmaxf((float)ph[2] + q4[2] + rv[2], 0.f);
    s[3] += fmaxf((float)ph[3] + q4[3] + rv[3], 0.f);
  }
  *(floatx4*)(&red[((jseg * 32 + r) * 8 + cg) * 4]) = s;
  __syncthreads();
  if (tid < 256) {
    int rr = tid >> 3, cc = tid & 7;
    int col2 = nt * 32 + cc * 4;
    floatx4 g = RED4(0, rr, cc) + RED4(1, rr, cc) + RED4(2, rr, cc) + RED4(3, rr, cc);
    *(floatx4*)(G2 + (size_t)(row0 + rr) * NF + col2) = g;
  }
}

// ---------------------------------------------------------------------------
// lin256: out = ReLU(A @ W + b).  K=256, N=256.  grid 256 = 32 Mt x 8 Nt.
// (predictor stage 1)
// ---------------------------------------------------------------------------
__global__ __launch_bounds__(1024) void lin256_kernel(
    const float* __restrict__ Ain, const float* __restrict__ W,
    const float* __restrict__ bias, float* __restrict__ outp)
{
  __shared__ __align__(16) float A[32 * 260];
  __shared__ __align__(16) float red[4096];
  int tid = threadIdx.x;
  int mt = blockIdx.x >> 3, nt = blockIdx.x & 7;
  int row0 = mt * 32;
  for (int idx = tid; idx < 2048; idx += 1024) {
    int rr = idx >> 6, q = idx & 63;
    *(floatx4*)(A + rr * 260 + q * 4) =
        *(const floatx4*)(Ain + (size_t)(row0 + rr) * NF + q * 4);
  }
  __syncthreads();
  int kseg = tid >> 8, r = (tid >> 3) & 31, cg = tid & 7;
  int col = nt * 32 + cg * 4;
  floatx4 acc = tile_part(W, NF, A, 260, kseg * 64, 16, r, col);
  *(floatx4*)(&red[((kseg * 32 + r) * 8 + cg) * 4]) = acc;
  __syncthreads();
  if (tid < 256) {
    int rr = tid >> 3, cc = tid & 7;
    int col2 = nt * 32 + cc * 4;
    floatx4 s = RED4(0, rr, cc) + RED4(1, rr, cc) + RED4(2, rr, cc) + RED4(3, rr, cc)
              + *(const floatx4*)(bias + col2);
    *(floatx4*)(outp + (size_t)(row0 + rr) * NF + col2) = relu4(s);
  }
}

// ---------------------------------------------------------------------------
// pred2: out = tanh(T @ w1 + b1).  K=256, N=32.  grid 32 (Mt only).
// ---------------------------------------------------------------------------
__global__ __launch_bounds__(1024) void pred2_kernel(
    const float* __restrict__ T, const float* __restrict__ w1,
    const float* __restrict__ b1, float* __restrict__ outp)
{
  __shared__ __align__(16) float A[32 * 260];
  __shared__ __align__(16) float red[4096];
  int tid = threadIdx.x;
  int row0 = blockIdx.x * 32;
  for (int idx = tid; idx < 2048; idx += 1024) {
    int rr = idx >> 6, q = idx & 63;
    *(floatx4*)(A + rr * 260 + q * 4) =
        *(const floatx4*)(T + (size_t)(row0 + rr) * NF + q * 4);
  }
  __syncthreads();
  int kseg = tid >> 8, r = (tid >> 3) & 31, cg = tid & 7;
  int col = cg * 4;                          // N = 32
  floatx4 acc = tile_part(w1, GG, A, 260, kseg * 64, 16, r, col);
  *(floatx4*)(&red[((kseg * 32 + r) * 8 + cg) * 4]) = acc;
  __syncthreads();
  if (tid < 256) {
    int rr = tid >> 3, cc = tid & 7;
    int col2 = cc * 4;
    floatx4 s = RED4(0, rr, cc) + RED4(1, rr, cc) + RED4(2, rr, cc) + RED4(3, rr, cc)
              + *(const floatx4*)(b1 + col2);
    s[0] = tanhf(s[0]); s[1] = tanhf(s[1]); s[2] = tanhf(s[2]); s[3] = tanhf(s[3]);
    *(floatx4*)(outp + (size_t)(row0 + rr) * GG + col2) = s;
  }
}

// ---------------------------------------------------------------------------
// Relation chain, fp16 A-split x B-single MFMA — EXACT R15 form (frozen;
// measured 58-62 us). HSTR=264 pad; no swizzle, no setprio.
// ---------------------------------------------------------------------------
#define ROWS 32
#define NRT 2
#define HSTR 264
#define XSTR 72

__global__ __launch_bounds__(256, 4) void rel_agg_store_mfma(
    const float* __restrict__ attrs, const float* __restrict__ states,
    const float* __restrict__ rel_attrs,
    const _Float16* __restrict__ F0, const float* __restrict__ b0,
    const _Float16* __restrict__ F1, const float* __restrict__ b1,
    const _Float16* __restrict__ F2,
    const float* __restrict__ Q, const float* __restrict__ R,
    _Float16* __restrict__ P, float* __restrict__ part)
{
  __shared__ __align__(16) _Float16 S[2 * ROWS * HSTR];   // 33792 B
  _Float16* Hh = S;
  _Float16* Hl = S + ROWS * HSTR;
  _Float16* Xh = Hh;   // X aliased onto H (dead after stage 1)
  _Float16* Xl = Hl;

  int tid  = threadIdx.x;
  int wave = tid >> 6;
  int lane = tid & 63;
  int quad = lane >> 4;
  int l16  = lane & 15;
  int row0 = blockIdx.x * ROWS;

  for (int idx = tid; idx < ROWS * 64; idx += 256) {
    int r = idx >> 6, k = idx & 63;
    int grow = row0 + r;
    int j = grow & 63, i = (grow >> 6) & 63, b = grow >> 12;
    float v = 0.f;
    if (k < RELD)                     v = rel_attrs[(size_t)grow * RELD + k];
    else if (k < RELD + STATE)        v = states[(b * NN + i) * STATE + (k - RELD)]
                                        - states[(b * NN + j) * STATE + (k - RELD)];
    else if (k < RELD + STATE + ATTR) v = attrs[(b * NN + i) * ATTR + (k - RELD - STATE)];
    else if (k < 33)                  v = attrs[(b * NN + j) * ATTR + (k - RELD - STATE - ATTR)];
    _Float16 h, l; split2h(v, h, l);
    Xh[r * XSTR + k] = h;
    Xl[r * XSTR + k] = l;
  }
  __syncthreads();

  floatx4 acc[NRT][4];

#define ZERO_ACC() do { \
  _Pragma("unroll") for (int rt = 0; rt < NRT; ++rt) \
  _Pragma("unroll") for (int ct = 0; ct < 4; ++ct) acc[rt][ct] = (floatx4)(0.f); } while (0)

#define STAGE(Sn, AH, AL, ASTR, BF) do { \
  half8 ah[2][NRT], al[2][NRT], bf[2][4]; \
  _Pragma("unroll") for (int ct = 0; ct < 4; ++ct) \
    bf[0][ct] = *(const half8*)((BF) + (size_t)((wave * 4 + ct) * 64 + lane) * 8); \
  _Pragma("unroll") for (int rt = 0; rt < NRT; ++rt) { \
    ah[0][rt] = *(const half8*)(&(AH)[(rt * 16 + l16) * (ASTR) + quad * 8]); \
    al[0][rt] = *(const half8*)(&(AL)[(rt * 16 + l16) * (ASTR) + quad * 8]); } \
  _Pragma("unroll") \
  for (int s = 0; s < (Sn); ++s) { \
    int cur = s & 1, nxt = cur ^ 1; \
    if (s + 1 < (Sn)) { \
      _Pragma("unroll") for (int ct = 0; ct < 4; ++ct) \
        bf[nxt][ct] = *(const half8*)((BF) + (size_t)(((s + 1) * 16 + wave * 4 + ct) * 64 + lane) * 8); \
      _Pragma("unroll") for (int rt = 0; rt < NRT; ++rt) { \
        ah[nxt][rt] = *(const half8*)(&(AH)[(rt * 16 + l16) * (ASTR) + (s + 1) * 32 + quad * 8]); \
        al[nxt][rt] = *(const half8*)(&(AL)[(rt * 16 + l16) * (ASTR) + (s + 1) * 32 + quad * 8]); } } \
    _Pragma("unroll") for (int rt = 0; rt < NRT; ++rt) \
    _Pragma("unroll") for (int ct = 0; ct < 4; ++ct) { \
      acc[rt][ct] = __builtin_amdgcn_mfma_f32_16x16x32_f16(ah[cur][rt], bf[cur][ct], acc[rt][ct], 0, 0, 0); \
      acc[rt][ct] = __builtin_amdgcn_mfma_f32_16x16x32_f16(al[cur][rt], bf[cur][ct], acc[rt][ct], 0, 0, 0); } \
  } } while (0)

  // ---- stage 1: H = ReLU(X @ W0 + b0), K=64 (padded)
  ZERO_ACC();
  STAGE(2, Xh, Xl, XSTR, F0);
  __syncthreads();  // X reads done before H overwrites the aliased region
#pragma unroll
  for (int ct = 0; ct < 4; ++ct) {
    int col = wave * 64 + ct * 16 + l16;
    float bias = b0[col];
#pragma unroll
    for (int rt = 0; rt < NRT; ++rt)
#pragma unroll
      for (int r = 0; r < 4; ++r) {
        int row = rt * 16 + quad * 4 + r;
        float h = fmaxf(acc[rt][ct][r] + bias, 0.f);
        split2h(h, Hh[row * HSTR + col], Hl[row * HSTR + col]);
      }
  }
  __syncthreads();

  // ---- stage 2: E = ReLU(H @ W1 + b1), K=256
  ZERO_ACC();
  STAGE(8, Hh, Hl, HSTR, F1);
  __syncthreads();
#pragma unroll
  for (int ct = 0; ct < 4; ++ct) {
    int col = wave * 64 + ct * 16 + l16;
    float bias = b1[col];
#pragma unroll
    for (int rt = 0; rt < NRT; ++rt)
#pragma unroll
      for (int r = 0; r < 4; ++r) {
        int row = rt * 16 + quad * 4 + r;
        float e = fmaxf(acc[rt][ct][r] + bias, 0.f);
        split2h(e, Hh[row * HSTR + col], Hl[row * HSTR + col]);
      }
  }
  __syncthreads();

  // ---- stage 3: P-tile in registers (K=256)
  ZERO_ACC();
  STAGE(8, Hh, Hl, HSTR, F2);

  // ---- store P fp16 (pstep 2 reads it in aggsweep)
#pragma unroll
  for (int ct = 0; ct < 4; ++ct) {
    int col = wave * 64 + ct * 16 + l16;
#pragma unroll
    for (int rt = 0; rt < NRT; ++rt)
#pragma unroll
      for (int r = 0; r < 4; ++r) {
        int row = rt * 16 + quad * 4 + r;
        P[(size_t)(row0 + row) * NF + col] = (_Float16)acc[rt][ct][r];
      }
  }
  __syncthreads();                       // all E reads done — LDS reusable

  // ---- fused pstep-1 aggregation epilogue (exact fp32 acc)
  {
    float* Rs = (float*)S;               // 32 x 256 fp32 R-tile (32KB)
    int bi    = row0 >> 6;
    int jbase = row0 & 63;               // 0 or 32
    int b     = row0 >> 12;
    for (int idx = tid; idx < ROWS * NF; idx += 256) {
      int rr = idx >> 8, cc = idx & 255;
      Rs[idx] = R[(size_t)(b * NN + jbase + rr) * NF + cc];
    }
    __syncthreads();
#pragma unroll
    for (int ct = 0; ct < 4; ++ct) {
      int col = wave * 64 + ct * 16 + l16;
      float q = Q[bi * NF + col];
      float s = 0.f;
#pragma unroll
      for (int rt = 0; rt < NRT; ++rt)
#pragma unroll
        for (int r = 0; r < 4; ++r) {
          int row = rt * 16 + quad * 4 + r;
          s += fmaxf(acc[rt][ct][r] + q + Rs[row * NF + col], 0.f);
        }
      s += __shfl_xor(s, 16, 64);        // quad butterfly: rows 0..31 summed
      s += __shfl_xor(s, 32, 64);
      if (quad == 0)
        part[((size_t)bi * 2 + (jbase >> 5)) * NF + col] = s;
    }
  }
#undef ZERO_ACC
#undef STAGE
}

extern "C" void kernel_launch(void* const* d_in, const int* in_sizes, int n_in,
                              void* d_out, int out_size, void* d_ws, size_t ws_size,
                              hipStream_t stream)
{
  const float* attrs     = (const float*)d_in[0];
  const float* states    = (const float*)d_in[1];
  const float* rel_attrs = (const float*)d_in[2];
  // d_in[3] = pstep (==2, structural)
  const float* enc_w0  = (const float*)d_in[4];
  const float* enc_b0  = (const float*)d_in[5];
  const float* enc_w1  = (const float*)d_in[6];
  const float* enc_b1  = (const float*)d_in[7];
  const float* rel_w0  = (const float*)d_in[8];
  const float* rel_b0  = (const float*)d_in[9];
  const float* rel_w1  = (const float*)d_in[10];
  const float* rel_b1  = (const float*)d_in[11];
  const float* rp_w    = (const float*)d_in[12];
  const float* rp_b    = (const float*)d_in[13];
  const float* pp_w    = (const float*)d_in[14];
  const float* pp_b    = (const float*)d_in[15];
  const float* pred_w0 = (const float*)d_in[16];
  const float* pred_b0 = (const float*)d_in[17];
  const float* pred_w1 = (const float*)d_in[18];
  const float* pred_b1 = (const float*)d_in[19];
  float* out = (float*)d_out;

  char* ws = (char*)d_ws;
  _Float16* P  = (_Float16*)ws;                             // 32 MB (fp16)
  float* obj0  = (float*)(ws + (size_t)NROWS_REL * NF * sizeof(_Float16));
  float* obj1  = obj0 + NROWS_OBJ * NF;
  float* Q0    = obj1 + NROWS_OBJ * NF;
  float* R0    = Q0 + NROWS_OBJ * NF;
  float* Q1    = R0 + NROWS_OBJ * NF;
  float* R1    = Q1 + NROWS_OBJ * NF;
  float* part1 = R1 + NROWS_OBJ * NF;                       // 2 MB
  _Float16* F0 = (_Float16*)(part1 + 2 * (size_t)NROWS_OBJ * NF);
  _Float16* F1 = F0 + F0_ELEMS;
  _Float16* F2 = F1 + F1_ELEMS;
  // dead-buffer reuse (no workspace growth):
  float* G2   = part1;   // part1 consumed by upd1 before aggsweep writes G2
  float* obj2 = obj0;    // obj0 consumed by upd1
  float* T    = Q0;      // Q0 consumed by rel

  enc_obj_kernel<<<256, 1024, 0, stream>>>(
      attrs, states, enc_w0, enc_b0, enc_w1, enc_b1, rp_w,
      rel_w0, rel_w1, F0, F1, F2, obj0);
  qr_kernel<<<512, 1024, 0, stream>>>(obj0, rp_w, rp_b, Q0, R0);
  // rel chain ONCE: fused pstep-1 agg + fp16 P store for pstep 2
  rel_agg_store_mfma<<<NROWS_REL / ROWS, 256, 0, stream>>>(
      attrs, states, rel_attrs,
      F0, rel_b0, F1, rel_b1, F2,
      Q0, R0, P, part1);
  upd_kernel<<<256, 1024, 0, stream>>>(obj0, part1, 1, pp_w, pp_b, obj1);
  qr_kernel<<<512, 1024, 0, stream>>>(obj1, rp_w, rp_b, Q1, R1);
  aggsweep_kernel<<<256, 1024, 0, stream>>>(P, Q1, R1, G2);
  upd_kernel<<<256, 1024, 0, stream>>>(obj1, G2, 0, pp_w, pp_b, obj2);
  lin256_kernel<<<256, 1024, 0, stream>>>(obj2, pred_w0, pred_b0, T);
  pred2_kernel<<<32, 1024, 0, stream>>>(T, pred_w1, pred_b1, out);
}